// Round 15
// baseline (744.174 us; speedup 1.0000x reference)
//
#include <hip/hip_runtime.h>
#include <stdint.h>

#define B 8192
#define T 512
#define K 24

__device__ __forceinline__ float max3f(float a, float b, float c) {
    return fmaxf(fmaxf(a, b), c);   // fuses to v_max3_f32
}

#define XG(v) __builtin_amdgcn_ds_swizzle((v), 0x101F)                 /* xor4 */
#define D2(v) __builtin_amdgcn_mov_dpp((v), 0x4E, 0xF, 0xF, true)      /* xor2 */
#define D1(v) __builtin_amdgcn_mov_dpp((v), 0xB1, 0xF, 0xF, true)      /* xor1 */

// One forward Viterbi step (round-11 proven). Butterfly all-gather of the
// 8-lane group's 24 alpha values (3 ds_swizzle xor4 + 6 DPP xor2 + 12 DPP
// xor1); slots land in lane-relative row order (slot 3k+c = row 3*(l^X[k])+c,
// X={0,4,2,6,1,5,3,7}) matching the tcr permutation done once at init.
// Order-free exact max via v_max3 tree; alpha row written to gp[0..2].
__device__ __forceinline__ void vstep(float& n0, float& n1, float& n2,
                                      float e0, float e1, float e2,
                                      const float (&tcr)[3][K], float* gp)
{
    const int i0 = __float_as_int(n0);
    const int i1 = __float_as_int(n1);
    const int i2 = __float_as_int(n2);
    const int b0 = XG(i0), b1 = XG(i1), b2 = XG(i2);
    const int q0 = D2(i0), q1 = D2(i1), q2 = D2(i2);
    const int q3 = D2(b0), q4 = D2(b1), q5 = D2(b2);
    const int d0 = D1(i0), d1 = D1(i1), d2  = D1(i2);
    const int d3 = D1(b0), d4 = D1(b1), d5  = D1(b2);
    const int d6 = D1(q0), d7 = D1(q1), d8  = D1(q2);
    const int d9 = D1(q3), d10 = D1(q4), d11 = D1(q5);

    float s[K];
    s[0]  = n0;                   s[1]  = n1;
    s[2]  = n2;                   s[3]  = __int_as_float(b0);
    s[4]  = __int_as_float(b1);   s[5]  = __int_as_float(b2);
    s[6]  = __int_as_float(q0);   s[7]  = __int_as_float(q1);
    s[8]  = __int_as_float(q2);   s[9]  = __int_as_float(q3);
    s[10] = __int_as_float(q4);   s[11] = __int_as_float(q5);
    s[12] = __int_as_float(d0);   s[13] = __int_as_float(d1);
    s[14] = __int_as_float(d2);   s[15] = __int_as_float(d3);
    s[16] = __int_as_float(d4);   s[17] = __int_as_float(d5);
    s[18] = __int_as_float(d6);   s[19] = __int_as_float(d7);
    s[20] = __int_as_float(d8);   s[21] = __int_as_float(d9);
    s[22] = __int_as_float(d10);  s[23] = __int_as_float(d11);

    float r[3];
#pragma unroll
    for (int j = 0; j < 3; ++j) {
        float u[8];
#pragma unroll
        for (int k = 0; k < 8; ++k)
            u[k] = max3f(s[3*k]   + tcr[j][3*k],
                         s[3*k+1] + tcr[j][3*k+1],
                         s[3*k+2] + tcr[j][3*k+2]);
        float w0 = max3f(u[0], u[1], u[2]);
        float w1 = max3f(u[3], u[4], u[5]);
        float w2 = fmaxf(u[6], u[7]);
        r[j] = max3f(w0, w1, w2);
    }
    n0 = r[0] + e0; n1 = r[1] + e1; n2 = r[2] + e2;
    gp[0] = n0; gp[1] = n1; gp[2] = n2;
}

// 32-lane-group max reduce, all lanes receive the max (round-9 proven).
__device__ __forceinline__ float groupmax32(float v) {
    float t;
    t = __int_as_float(__builtin_amdgcn_mov_dpp(__float_as_int(v), 0xB1, 0xF, 0xF, true));   // xor1
    v = fmaxf(v, t);
    t = __int_as_float(__builtin_amdgcn_mov_dpp(__float_as_int(v), 0x4E, 0xF, 0xF, true));   // xor2
    v = fmaxf(v, t);
    t = __int_as_float(__builtin_amdgcn_mov_dpp(__float_as_int(v), 0x141, 0xF, 0xF, true));  // row_half_mirror
    v = fmaxf(v, t);
    t = __int_as_float(__builtin_amdgcn_mov_dpp(__float_as_int(v), 0x140, 0xF, 0xF, true));  // row_mirror
    v = fmaxf(v, t);
    t = __int_as_float(__builtin_amdgcn_ds_swizzle(__float_as_int(v), 0x401F));              // xor16
    v = fmaxf(v, t);
    return v;
}

// ---------------------------------------------------------------------------
// FUSED forward + backtrack. 64-thread block = one wave = 8 batches.
// Phase 1 (round-11 forward, verbatim): value-only Viterbi, register alpha,
//   DPP/swizzle exchange, 4-deep emission prefetch; alpha_t -> d_out[b][t][:].
// __threadfence(): drain stores + invalidate L1 so the wave can read rows
//   written by its sibling lanes.
// Phase 2: backtrack the block's own 8 batches as 4 pairs INTERLEAVED
//   (4 independent chains fill the ~100-cyc serial argmax latency). Per pair:
//   32 lanes/batch, 8-deep alpha prefetch, trans[i][cur] from stride-25 LDS,
//   DPP value-max + ballot/ctz exact first-index argmax, one-hot overwrite
//   in place. Recent-t alpha is L2-hot (just written by this block).
// ---------------------------------------------------------------------------
__global__ __launch_bounds__(64) __attribute__((amdgpu_waves_per_eu(1, 1)))
void crf_fused(const float* __restrict__ inp,    // [B, T, K]
               const float* __restrict__ trans,  // [K, K] (prev i -> cur j)
               float* __restrict__ out)          // [B, T, K]
{
    __shared__ float tl[K * 25];           // tl[i*25 + j] = trans[i][j]

    const int lane = threadIdx.x;          // one wave per block
    for (int idx = lane; idx < K * K; idx += 64) {
        int i = idx / K, j = idx - K * i;
        tl[i * 25 + j] = trans[idx];
    }
    // single wave: in-order DS pipe + compiler waitcnt -> no barrier needed

    // ======================= Phase 1: forward =============================
    {
        const int g  = lane >> 3;            // batch group 0..7
        const int l  = lane & 7;             // lane within group
        const int c0 = 3 * l;                // this lane's columns c0..c0+2
        const int b  = blockIdx.x * 8 + g;   // 1024 blocks * 8 = 8192

        const int X[8] = {0, 4, 2, 6, 1, 5, 3, 7};
        float tcr[3][K];
#pragma unroll
        for (int j = 0; j < 3; ++j)
#pragma unroll
            for (int k = 0; k < 8; ++k) {
                const int rl = 3 * (l ^ X[k]);
#pragma unroll
                for (int c = 0; c < 3; ++c)
                    tcr[j][3 * k + c] = trans[(rl + c) * K + c0 + j];
            }

        const float* ebl = inp + (size_t)b * T * K + c0;
        float*       obl = out + (size_t)b * T * K + c0;

        float n0, n1, n2;
        n0 = ebl[0]; n1 = ebl[1]; n2 = ebl[2];
        obl[0] = n0; obl[1] = n1; obl[2] = n2;

        float eA0 = ebl[1*K], eA1 = ebl[1*K+1], eA2 = ebl[1*K+2];
        float eB0 = ebl[2*K], eB1 = ebl[2*K+1], eB2 = ebl[2*K+2];
        float eC0 = ebl[3*K], eC1 = ebl[3*K+1], eC2 = ebl[3*K+2];
        float eD0 = ebl[4*K], eD1 = ebl[4*K+1], eD2 = ebl[4*K+2];

#pragma unroll 1
        for (int ch = 0; ch < 127; ++ch) {
            const int t = 1 + 4 * ch;              // 1,5,...,505
            const float* p4 = ebl + (size_t)(t + 4) * K;
            const float* p5 = ebl + (size_t)(t + 5) * K;
            const float* p6 = ebl + (size_t)(t + 6) * K;
            int t7 = t + 7; t7 = t7 > 511 ? 511 : t7;
            const float* p7 = ebl + (size_t)t7 * K;
            float nA0 = p4[0], nA1 = p4[1], nA2 = p4[2];
            float nB0 = p5[0], nB1 = p5[1], nB2 = p5[2];
            float nC0 = p6[0], nC1 = p6[1], nC2 = p6[2];
            float nD0 = p7[0], nD1 = p7[1], nD2 = p7[2];

            vstep(n0, n1, n2, eA0, eA1, eA2, tcr, obl + (size_t)(t    ) * K);
            vstep(n0, n1, n2, eB0, eB1, eB2, tcr, obl + (size_t)(t + 1) * K);
            vstep(n0, n1, n2, eC0, eC1, eC2, tcr, obl + (size_t)(t + 2) * K);
            vstep(n0, n1, n2, eD0, eD1, eD2, tcr, obl + (size_t)(t + 3) * K);

            eA0 = nA0; eA1 = nA1; eA2 = nA2;
            eB0 = nB0; eB1 = nB1; eB2 = nB2;
            eC0 = nC0; eC1 = nC1; eC2 = nC2;
            eD0 = nD0; eD1 = nD1; eD2 = nD2;
        }
        vstep(n0, n1, n2, eA0, eA1, eA2, tcr, obl + (size_t)509 * K);
        vstep(n0, n1, n2, eB0, eB1, eB2, tcr, obl + (size_t)510 * K);
        vstep(n0, n1, n2, eC0, eC1, eC2, tcr, obl + (size_t)511 * K);
    }

    __threadfence();   // stores -> L2 visible, L1 invalidated

    // ======================= Phase 2: backtrack ===========================
    const int half = lane >> 5;            // batch within pair (0/1)
    const int i32  = lane & 31;            // tag row (24..31 idle)
    const int shmt = half * 32;
    const bool act = (i32 < K);
    const int  io  = act ? i32 : (K - 1);

    const float* rp[4];
    float*       wp[4];
    int          cur[4];
    float        q[4][8];

#pragma unroll
    for (int p = 0; p < 4; ++p) {
        const int bb = blockIdx.x * 8 + 2 * p + half;
        float* obp = out + (size_t)bb * T * K;
        rp[p] = obp + (size_t)511 * K + io;
        wp[p] = obp + (size_t)511 * K + io;
    }

    // prologue: slots for t = 511..504, all 4 pairs interleaved
#pragma unroll
    for (int s = 0; s < 8; ++s)
#pragma unroll
        for (int p = 0; p < 4; ++p) { q[p][7 - s] = *rp[p]; rp[p] -= K; }

    // t = 511: last_tag = first-index argmax of alpha_511
#pragma unroll
    for (int p = 0; p < 4; ++p) {
        float s = act ? q[p][7] : -INFINITY;
        float M = groupmax32(s);
        uint32_t m32 = (uint32_t)(__ballot(s == M) >> shmt);
        cur[p] = (int)__builtin_ctz(m32);
        if (act) *wp[p] = (i32 == cur[p]) ? 1.0f : 0.0f;
        wp[p] -= K;
        q[p][7] = *rp[p]; rp[p] -= K;      // prefetch t=503 into slot 7
    }

#define STEP_BT(S, TT) do {                                                   \
    _Pragma("unroll")                                                         \
    for (int p = 0; p < 4; ++p) {                                             \
        float tv_ = tl[io * 25 + cur[p]];                                     \
        float s_  = act ? (q[p][S] + tv_) : -INFINITY;                        \
        float M_  = groupmax32(s_);                                           \
        uint32_t m32_ = (uint32_t)(__ballot(s_ == M_) >> shmt);               \
        cur[p] = (int)__builtin_ctz(m32_);                                    \
        if (act) *wp[p] = (i32 == cur[p]) ? 1.0f : 0.0f;                      \
        wp[p] -= K;                                                           \
        if ((TT) >= 8) { q[p][S] = *rp[p]; rp[p] -= K; }                      \
    }                                                                         \
} while (0)

#pragma unroll 1
    for (int it = 0; it < 63; ++it) {      // t = 510 .. 7
        const int t0 = 510 - 8 * it;
        STEP_BT(6, t0);     STEP_BT(5, t0 - 1);
        STEP_BT(4, t0 - 2); STEP_BT(3, t0 - 3);
        STEP_BT(2, t0 - 4); STEP_BT(1, t0 - 5);
        STEP_BT(0, t0 - 6); STEP_BT(7, t0 - 7);
    }
    // epilogue: t = 6..0 (all slots resident)
    STEP_BT(6, 6); STEP_BT(5, 5); STEP_BT(4, 4);
    STEP_BT(3, 3); STEP_BT(2, 2); STEP_BT(1, 1); STEP_BT(0, 0);
#undef STEP_BT
}

#undef XG
#undef D2
#undef D1

extern "C" void kernel_launch(void* const* d_in, const int* in_sizes, int n_in,
                              void* d_out, int out_size, void* d_ws, size_t ws_size,
                              hipStream_t stream) {
    const float* inp   = (const float*)d_in[0];   // [8192, 512, 24]
    const float* trans = (const float*)d_in[1];   // [24, 24]
    float*       out   = (float*)d_out;           // [8192, 512, 24]

    crf_fused<<<B / 8, 64, 0, stream>>>(inp, trans, out);
}

// Round 16
// 335.125 us; speedup vs baseline: 2.2206x; 2.2206x over previous
//
#include <hip/hip_runtime.h>
#include <stdint.h>

#define B 8192
#define T 512
#define K 24

__device__ __forceinline__ float max3f(float a, float b, float c) {
    return fmaxf(fmaxf(a, b), c);   // fuses to v_max3_f32
}

// ---------------------------------------------------------------------------
// Forward Viterbi, VALUE-ONLY, REGISTER-RESIDENT alpha (no LDS buffer).
// 64-thread block = one wave = 8 batches (8-lane group x 3 cols/lane).
// Per-step all-gather of the group's 24 alpha values via butterfly:
//   stage xor4: 3 x ds_swizzle (LDS crossbar only, no memory traffic)
//   stage xor2: 6 x DPP quad_perm [2,3,0,1]   (VALU pipe)
//   stage xor1: 12 x DPP quad_perm [1,0,3,2]  (VALU pipe)
// Gathered slots are in LANE-RELATIVE row order: slot 3k+c holds row
// 3*(l^X[k])+c with X={0,4,2,6,1,5,3,7} — a static function of lane, so the
// transition coefficients are permuted identically ONCE at init and the
// (order-free, exact) add+max3 tree is unchanged. No barriers, no LDS
// write->read round trip. 4-step-deep emission prefetch ring.
// Alpha_t streams to d_out[b][t][:]; backtrack recomputes exact argmax.
// ---------------------------------------------------------------------------
__global__ __launch_bounds__(64) __attribute__((amdgpu_waves_per_eu(1, 1)))
void crf_forward(const float* __restrict__ inp,    // [B, T, K]
                 const float* __restrict__ trans,  // [K, K] (prev i -> cur j)
                 float* __restrict__ out)          // [B, T, K] <- alpha
{
    const int lane = threadIdx.x;          // one wave per block
    const int g    = lane >> 3;            // batch group 0..7
    const int l    = lane & 7;             // lane within group
    const int c0   = 3 * l;                // this lane's columns c0..c0+2
    const int b    = blockIdx.x * 8 + g;   // 1024 blocks * 8 = 8192

    // tc permuted to gather order: tcr[j][3k+c] = trans[3*(l^X[k])+c][c0+j]
    const int X[8] = {0, 4, 2, 6, 1, 5, 3, 7};
    float tcr[3][K];
#pragma unroll
    for (int j = 0; j < 3; ++j)
#pragma unroll
        for (int k = 0; k < 8; ++k) {
            const int rl = 3 * (l ^ X[k]);
#pragma unroll
            for (int c = 0; c < 3; ++c)
                tcr[j][3 * k + c] = trans[(rl + c) * K + c0 + j];
        }

    const float* ebl = inp + (size_t)b * T * K + c0;
    float*       obl = out + (size_t)b * T * K + c0;

    float n0, n1, n2;                      // own alpha rows 3l..3l+2
    {   // t = 0: alpha_0 = emissions_0
        n0 = ebl[0]; n1 = ebl[1]; n2 = ebl[2];
        obl[0] = n0; obl[1] = n1; obl[2] = n2;
    }

    // emission ring: eA..eD hold e(t)..e(t+3) for the current chunk
    float eA0 = ebl[1*K], eA1 = ebl[1*K+1], eA2 = ebl[1*K+2];
    float eB0 = ebl[2*K], eB1 = ebl[2*K+1], eB2 = ebl[2*K+2];
    float eC0 = ebl[3*K], eC1 = ebl[3*K+1], eC2 = ebl[3*K+2];
    float eD0 = ebl[4*K], eD1 = ebl[4*K+1], eD2 = ebl[4*K+2];

#define XG(v) __builtin_amdgcn_ds_swizzle((v), 0x101F)                 /* xor4 */
#define D2(v) __builtin_amdgcn_mov_dpp((v), 0x4E, 0xF, 0xF, true)      /* xor2 */
#define D1(v) __builtin_amdgcn_mov_dpp((v), 0xB1, 0xF, 0xF, true)      /* xor1 */

#define STEP(E0, E1, E2, TT) do {                                             \
    const int i0_ = __float_as_int(n0);                                       \
    const int i1_ = __float_as_int(n1);                                       \
    const int i2_ = __float_as_int(n2);                                       \
    const int b0_ = XG(i0_), b1_ = XG(i1_), b2_ = XG(i2_);                    \
    const int q0_ = D2(i0_), q1_ = D2(i1_), q2_ = D2(i2_);                    \
    const int q3_ = D2(b0_), q4_ = D2(b1_), q5_ = D2(b2_);                    \
    const int d0_ = D1(i0_), d1_ = D1(i1_), d2_  = D1(i2_);                   \
    const int d3_ = D1(b0_), d4_ = D1(b1_), d5_  = D1(b2_);                   \
    const int d6_ = D1(q0_), d7_ = D1(q1_), d8_  = D1(q2_);                   \
    const int d9_ = D1(q3_), d10_ = D1(q4_), d11_ = D1(q5_);                  \
    float s_[K];                                                              \
    s_[0]  = n0;                    s_[1]  = n1;                              \
    s_[2]  = n2;                    s_[3]  = __int_as_float(b0_);             \
    s_[4]  = __int_as_float(b1_);   s_[5]  = __int_as_float(b2_);             \
    s_[6]  = __int_as_float(q0_);   s_[7]  = __int_as_float(q1_);             \
    s_[8]  = __int_as_float(q2_);   s_[9]  = __int_as_float(q3_);             \
    s_[10] = __int_as_float(q4_);   s_[11] = __int_as_float(q5_);             \
    s_[12] = __int_as_float(d0_);   s_[13] = __int_as_float(d1_);             \
    s_[14] = __int_as_float(d2_);   s_[15] = __int_as_float(d3_);             \
    s_[16] = __int_as_float(d4_);   s_[17] = __int_as_float(d5_);             \
    s_[18] = __int_as_float(d6_);   s_[19] = __int_as_float(d7_);             \
    s_[20] = __int_as_float(d8_);   s_[21] = __int_as_float(d9_);             \
    s_[22] = __int_as_float(d10_);  s_[23] = __int_as_float(d11_);            \
    float r_[3];                                                              \
    _Pragma("unroll")                                                         \
    for (int j = 0; j < 3; ++j) {                                             \
        float u_[8];                                                          \
        _Pragma("unroll")                                                     \
        for (int k = 0; k < 8; ++k)                                           \
            u_[k] = max3f(s_[3*k]   + tcr[j][3*k],                            \
                          s_[3*k+1] + tcr[j][3*k+1],                          \
                          s_[3*k+2] + tcr[j][3*k+2]);                         \
        float w0_ = max3f(u_[0], u_[1], u_[2]);                               \
        float w1_ = max3f(u_[3], u_[4], u_[5]);                               \
        float w2_ = fmaxf(u_[6], u_[7]);                                      \
        r_[j] = max3f(w0_, w1_, w2_);                                         \
    }                                                                         \
    n0 = r_[0] + (E0); n1 = r_[1] + (E1); n2 = r_[2] + (E2);                  \
    float* gp_ = obl + (size_t)(TT) * K;                                      \
    gp_[0] = n0; gp_[1] = n1; gp_[2] = n2;                                    \
} while (0)

#pragma unroll 1
    for (int ch = 0; ch < 127; ++ch) {
        const int t = 1 + 4 * ch;              // 1,5,...,505
        // preload e(t+4..t+7); only t+7 can run past the end (clamped)
        const float* p4 = ebl + (size_t)(t + 4) * K;
        const float* p5 = ebl + (size_t)(t + 5) * K;
        const float* p6 = ebl + (size_t)(t + 6) * K;
        int t7 = t + 7; t7 = t7 > 511 ? 511 : t7;
        const float* p7 = ebl + (size_t)t7 * K;
        float nA0 = p4[0], nA1 = p4[1], nA2 = p4[2];
        float nB0 = p5[0], nB1 = p5[1], nB2 = p5[2];
        float nC0 = p6[0], nC1 = p6[1], nC2 = p6[2];
        float nD0 = p7[0], nD1 = p7[1], nD2 = p7[2];

        STEP(eA0, eA1, eA2, t);
        STEP(eB0, eB1, eB2, t + 1);
        STEP(eC0, eC1, eC2, t + 2);
        STEP(eD0, eD1, eD2, t + 3);

        eA0 = nA0; eA1 = nA1; eA2 = nA2;
        eB0 = nB0; eB1 = nB1; eB2 = nB2;
        eC0 = nC0; eC1 = nC1; eC2 = nC2;
        eD0 = nD0; eD1 = nD1; eD2 = nD2;
    }
    // tail: t = 509, 510, 511 (eA..eC already hold their emissions)
    STEP(eA0, eA1, eA2, 509);
    STEP(eB0, eB1, eB2, 510);
    STEP(eC0, eC1, eC2, 511);
#undef STEP
#undef XG
#undef D2
#undef D1
}

// ---------------------------------------------------------------------------
// 32-lane-group max reduce, all lanes receive the max. 4 DPP steps (VALU
// latency) + 1 ds_swizzle xor-16. Exact (fmax of finite floats).
// ---------------------------------------------------------------------------
__device__ __forceinline__ float groupmax32(float v) {
    float t;
    t = __int_as_float(__builtin_amdgcn_mov_dpp(__float_as_int(v), 0xB1, 0xF, 0xF, true));   // quad_perm [1,0,3,2]
    v = fmaxf(v, t);
    t = __int_as_float(__builtin_amdgcn_mov_dpp(__float_as_int(v), 0x4E, 0xF, 0xF, true));   // quad_perm [2,3,0,1]
    v = fmaxf(v, t);
    t = __int_as_float(__builtin_amdgcn_mov_dpp(__float_as_int(v), 0x141, 0xF, 0xF, true));  // row_half_mirror
    v = fmaxf(v, t);
    t = __int_as_float(__builtin_amdgcn_mov_dpp(__float_as_int(v), 0x140, 0xF, 0xF, true));  // row_mirror
    v = fmaxf(v, t);
    t = __int_as_float(__builtin_amdgcn_ds_swizzle(__float_as_int(v), 0x401F));              // xor 16
    v = fmaxf(v, t);
    return v;
}

// ---------------------------------------------------------------------------
// Fused backtrack + one-hot (measured at the HBM floor, ~5.6 TB/s).
// 32 lanes per batch, 2 batches/wave, 4096 waves. Per step: prefetched
// alpha_t[i] (8-deep rotation) + trans[i][cur] from stride-25 LDS -> DPP
// value-max -> cur = ctz(ballot(s == M)) (exact first-index) -> one-hot.
// ---------------------------------------------------------------------------
__global__ __launch_bounds__(256) __attribute__((amdgpu_waves_per_eu(4, 4)))
void crf_backtrack(const float* __restrict__ trans,  // [K, K]
                   float* __restrict__ out)          // [B,T,K] alpha->onehot
{
    __shared__ float tl[K * 25];      // tl[i*25 + j] = trans[i][j]

    const int tid = threadIdx.x;
    for (int idx = tid; idx < K * K; idx += 256) {
        int i = idx / K, j = idx - K * i;
        tl[i * 25 + j] = trans[idx];
    }
    __syncthreads();

    const int lane = tid & 63;
    const int half = lane >> 5;            // batch within wave (0/1)
    const int i    = lane & 31;            // tag row (24..31 idle)
    const int wv   = tid >> 6;
    const int b    = blockIdx.x * 8 + wv * 2 + half;
    const int shmt = half * 32;

    const bool act = (i < K);
    const int  io  = act ? i : (K - 1);

    float* ob = out + (size_t)b * T * K;
    const float* rp  = ob + (size_t)511 * K + io;   // prefetch pointer
    float*       wpp = ob + (size_t)511 * K + io;   // write pointer

    float q[8];                            // slot = t & 7
#pragma unroll
    for (int s = 0; s < 8; ++s) { q[7 - s] = *rp; rp -= K; }   // t=511..504

    int cur;
    {   // t = 511: last_tag = first-index argmax of alpha_511
        float s = act ? q[7] : -INFINITY;
        float M = groupmax32(s);
        uint32_t m32 = (uint32_t)(__ballot(s == M) >> shmt);
        cur = (int)__builtin_ctz(m32);
        if (act) *wpp = (i == cur) ? 1.0f : 0.0f;
        wpp -= K;
        q[7] = *rp; rp -= K;               // prefetch t=503 into slot 7
    }

#define STEP_BT(S, TT) do {                                                   \
    float tv_ = tl[io * 25 + cur];                                            \
    float s_  = act ? (q[S] + tv_) : -INFINITY;                               \
    float M_  = groupmax32(s_);                                               \
    uint32_t m32_ = (uint32_t)(__ballot(s_ == M_) >> shmt);                   \
    cur = (int)__builtin_ctz(m32_);                                           \
    if (act) *wpp = (i == cur) ? 1.0f : 0.0f;                                 \
    wpp -= K;                                                                 \
    if ((TT) >= 8) { q[S] = *rp; rp -= K; }                                   \
} while (0)

#pragma unroll 1
    for (int it = 0; it < 63; ++it) {      // t = 510 .. 7
        const int t0 = 510 - 8 * it;
        STEP_BT(6, t0);     STEP_BT(5, t0 - 1);
        STEP_BT(4, t0 - 2); STEP_BT(3, t0 - 3);
        STEP_BT(2, t0 - 4); STEP_BT(1, t0 - 5);
        STEP_BT(0, t0 - 6); STEP_BT(7, t0 - 7);
    }
    // epilogue: t = 6..0 (all slots already resident)
    STEP_BT(6, 6); STEP_BT(5, 5); STEP_BT(4, 4);
    STEP_BT(3, 3); STEP_BT(2, 2); STEP_BT(1, 1); STEP_BT(0, 0);
#undef STEP_BT
}

extern "C" void kernel_launch(void* const* d_in, const int* in_sizes, int n_in,
                              void* d_out, int out_size, void* d_ws, size_t ws_size,
                              hipStream_t stream) {
    const float* inp   = (const float*)d_in[0];   // [8192, 512, 24]
    const float* trans = (const float*)d_in[1];   // [24, 24]
    float*       out   = (float*)d_out;           // [8192, 512, 24]

    crf_forward<<<B / 8, 64, 0, stream>>>(inp, trans, out);
    crf_backtrack<<<B / 8, 256, 0, stream>>>(trans, out);
}